// Round 2
// baseline (392.391 us; speedup 1.0000x reference)
//
#include <hip/hip_runtime.h>

typedef __attribute__((ext_vector_type(8))) short s16x8;
typedef __attribute__((ext_vector_type(4))) float f32x4;

#define MFMA16(a, b, c) __builtin_amdgcn_mfma_f32_16x16x32_bf16((a), (b), (c), 0, 0, 0)

__device__ __forceinline__ ushort f2bf(float f) {
  uint u = __builtin_bit_cast(uint, f);
  u = (u + 0x7fffu + ((u >> 16) & 1u)) >> 16;
  return (ushort)u;
}

// ---------------- weight fp32 -> bf16 ----------------
__global__ __launch_bounds__(256) void cvt_w_kernel(
    const float* __restrict__ s0, const float* __restrict__ s1,
    const float* __restrict__ s2, const float* __restrict__ s3,
    ushort* __restrict__ d0, ushort* __restrict__ d1,
    ushort* __restrict__ d2, ushort* __restrict__ d3) {
  int i = blockIdx.x * 256 + threadIdx.x;  // [0, 16384) float4 over 65536 elems
  const float4* s[4] = {(const float4*)s0, (const float4*)s1, (const float4*)s2, (const float4*)s3};
  ushort* d[4] = {d0, d1, d2, d3};
#pragma unroll
  for (int m = 0; m < 4; ++m) {
    float4 v = s[m][i];
    uint lo = (uint)f2bf(v.x) | ((uint)f2bf(v.y) << 16);
    uint hi = (uint)f2bf(v.z) | ((uint)f2bf(v.w) << 16);
    *(uint2*)(d[m] + (size_t)i * 4) = make_uint2(lo, hi);
  }
}

// ---------------- GroupNorm stats -> per-channel scale/shift ----------------
__global__ __launch_bounds__(256) void gn_stats_kernel(
    const float* __restrict__ x, const float* __restrict__ gw,
    const float* __restrict__ gb, float* __restrict__ scaleB,
    float* __restrict__ shiftB) {
  int b = blockIdx.x >> 3, g = blockIdx.x & 7;
  const float4* src = (const float4*)(x + ((size_t)b * 256 + g * 32) * 4096);
  float s = 0.f, ss = 0.f;
  for (int i = threadIdx.x; i < 32768; i += 256) {
    float4 v = src[i];
    s += v.x + v.y + v.z + v.w;
    ss += v.x * v.x + v.y * v.y + v.z * v.z + v.w * v.w;
  }
#pragma unroll
  for (int off = 32; off; off >>= 1) {
    s += __shfl_down(s, off);
    ss += __shfl_down(ss, off);
  }
  __shared__ float ps[4], pss[4];
  __shared__ float smu, srs;
  int w = threadIdx.x >> 6, lane = threadIdx.x & 63;
  if (lane == 0) { ps[w] = s; pss[w] = ss; }
  __syncthreads();
  if (threadIdx.x == 0) {
    float S = ps[0] + ps[1] + ps[2] + ps[3];
    float SS = pss[0] + pss[1] + pss[2] + pss[3];
    float mu = S * (1.f / 131072.f);
    float var = SS * (1.f / 131072.f) - mu * mu;
    smu = mu;
    srs = rsqrtf(var + 1e-5f);
  }
  __syncthreads();
  if (threadIdx.x < 32) {
    int ch = g * 32 + threadIdx.x;
    float sc = gw[ch] * srs;
    scaleB[b * 256 + ch] = sc;
    shiftB[b * 256 + ch] = gb[ch] - smu * sc;
  }
}

// ---------------- GN apply + transpose: x[b][c][n] -> y[b][n][c] bf16 ----------------
__global__ __launch_bounds__(256) void gn_apply_kernel(
    const float* __restrict__ x, const float* __restrict__ scaleB,
    const float* __restrict__ shiftB, ushort* __restrict__ y) {
  int bid = blockIdx.x;
  int b = bid >> 8;
  int rem = bid & 255;
  int ct = rem >> 6, nt = rem & 63;  // 64-channel x 64-n tile
  int t = threadIdx.x;
  __shared__ float xs[64][65];
  const float* xb = x + ((size_t)b * 256 + ct * 64) * 4096 + nt * 64;
  {
    int r = t >> 2, q = t & 3;
    const float4* src = (const float4*)(xb + (size_t)r * 4096 + q * 16);
#pragma unroll
    for (int i = 0; i < 4; ++i) {
      float4 v = src[i];
      xs[r][q * 16 + i * 4 + 0] = v.x;
      xs[r][q * 16 + i * 4 + 1] = v.y;
      xs[r][q * 16 + i * 4 + 2] = v.z;
      xs[r][q * 16 + i * 4 + 3] = v.w;
    }
  }
  __syncthreads();
  {
    int nr = t >> 2, q = t & 3;
    int c0 = q * 16;
    ushort tmp[16];
#pragma unroll
    for (int i = 0; i < 16; ++i) {
      int ch = ct * 64 + c0 + i;
      float v = xs[c0 + i][nr] * scaleB[b * 256 + ch] + shiftB[b * 256 + ch];
      tmp[i] = f2bf(v);
    }
    ushort* dst = y + ((size_t)b * 4096 + nt * 64 + nr) * 256 + ct * 64 + c0;
    uint p[8];
#pragma unroll
    for (int j = 0; j < 8; ++j) p[j] = (uint)tmp[2 * j] | ((uint)tmp[2 * j + 1] << 16);
    *(uint4*)dst = make_uint4(p[0], p[1], p[2], p[3]);
    *((uint4*)dst + 1) = make_uint4(p[4], p[5], p[6], p[7]);
  }
}

// ---------------- GEMM: C[M][N] = A[M][256] . B[N][256]^T (+bias, +resid) ----------------
// MODE 0: bf16 out, bias over col (N). MODE 1: bf16 out, bias over row (M).
// MODE 2: f32 out, bias over row + residual add.
template <int MODE>
__global__ __launch_bounds__(256) void gemm_bt(
    const ushort* __restrict__ A, const ushort* __restrict__ B,
    size_t aB, size_t bB, int M, int N,
    const float* __restrict__ bias, const float* __restrict__ resid,
    size_t rB, void* __restrict__ Cout, size_t cB) {
  int mTiles = M >> 7;
  int tm = blockIdx.x % mTiles, tn = blockIdx.x / mTiles;
  const ushort* Ab = A + blockIdx.y * aB + (size_t)tm * 128 * 256;
  const ushort* Bb = B + blockIdx.y * bB + (size_t)tn * 128 * 256;

  __shared__ ushort As[128 * 72];
  __shared__ ushort Bs[128 * 72];

  int t = threadIdx.x, lane = t & 63, w = t >> 6;
  int wr = w >> 1, wc = w & 1, lq = lane & 15, lg = lane >> 4;

  f32x4 acc[4][4];
#pragma unroll
  for (int i = 0; i < 4; ++i)
#pragma unroll
    for (int j = 0; j < 4; ++j) acc[i][j] = f32x4{0.f, 0.f, 0.f, 0.f};

  int srow = t >> 1, shalf = t & 1;
#pragma unroll 1
  for (int kb = 0; kb < 4; ++kb) {
    __syncthreads();
    {
      const ushort* sa = Ab + (size_t)srow * 256 + kb * 64 + shalf * 32;
      const ushort* sb = Bb + (size_t)srow * 256 + kb * 64 + shalf * 32;
      ushort* da = &As[srow * 72 + shalf * 32];
      ushort* db = &Bs[srow * 72 + shalf * 32];
#pragma unroll
      for (int j = 0; j < 4; ++j) {
        *(uint4*)(da + j * 8) = *(const uint4*)(sa + j * 8);
        *(uint4*)(db + j * 8) = *(const uint4*)(sb + j * 8);
      }
    }
    __syncthreads();
#pragma unroll
    for (int ks = 0; ks < 2; ++ks) {
      s16x8 af[4], bf[4];
#pragma unroll
      for (int mt = 0; mt < 4; ++mt)
        af[mt] = *(const s16x8*)&As[(wr * 64 + mt * 16 + lq) * 72 + ks * 32 + lg * 8];
#pragma unroll
      for (int nt = 0; nt < 4; ++nt)
        bf[nt] = *(const s16x8*)&Bs[(wc * 64 + nt * 16 + lq) * 72 + ks * 32 + lg * 8];
#pragma unroll
      for (int mt = 0; mt < 4; ++mt)
#pragma unroll
        for (int nt = 0; nt < 4; ++nt)
          acc[mt][nt] = MFMA16(af[mt], bf[nt], acc[mt][nt]);
    }
  }

  int mBase = tm * 128 + wr * 64;
  int nBase = tn * 128 + wc * 64;
#pragma unroll
  for (int mt = 0; mt < 4; ++mt) {
#pragma unroll
    for (int nt = 0; nt < 4; ++nt) {
#pragma unroll
      for (int r = 0; r < 4; ++r) {
        int row = mBase + mt * 16 + lg * 4 + r;
        int col = nBase + nt * 16 + lq;
        size_t idx = (size_t)row * N + col;
        float v = acc[mt][nt][r];
        if (MODE == 0) v += bias[col];
        else v += bias[row];
        if (MODE == 2) {
          float* C = (float*)Cout + blockIdx.y * cB;
          C[idx] = v + resid[blockIdx.y * rB + idx];
        } else {
          ushort* C = (ushort*)Cout + blockIdx.y * cB;
          C[idx] = f2bf(v);
        }
      }
    }
  }
}

// ---------------- Flash attention ----------------
// q[b][n][256], k[b][n][256] (k'[m][o]), vT[b][256][n] -> o[b][n][256], all bf16
__global__ __launch_bounds__(256) void attn_kernel(
    const ushort* __restrict__ q, const ushort* __restrict__ k,
    const ushort* __restrict__ vT, ushort* __restrict__ o) {
  int bb = blockIdx.x & 7;
  int qt = blockIdx.x >> 3;
  int t = threadIdx.x, w = t >> 6, lane = t & 63, lq = lane & 15, lg = lane >> 4;

  __shared__ ushort Kls[32 * 264];     // [k][c], pad 8
  __shared__ ushort Vls[256 * 40];     // [d][k], pad 8
  __shared__ ushort Pls[4][16 * 40];   // per-wave [q][k], pad 8
  __shared__ float as_[4][16];
  __shared__ float ls_[4][16];

  s16x8 qf[8];
  {
    const ushort* qp = q + ((size_t)(bb * 4096 + qt * 64 + w * 16 + lq)) * 256 + lg * 8;
#pragma unroll
    for (int ct = 0; ct < 8; ++ct) qf[ct] = *(const s16x8*)(qp + ct * 32);
  }
  f32x4 oacc[16];
#pragma unroll
  for (int i = 0; i < 16; ++i) oacc[i] = f32x4{0.f, 0.f, 0.f, 0.f};
  float mrun = -1e30f, lrun = 0.f;

  const ushort* kbase = k + (size_t)bb * 4096 * 256;
  const ushort* vbase = vT + (size_t)bb * 256 * 4096;

#pragma unroll 1
  for (int kv = 0; kv < 128; ++kv) {
    __syncthreads();
    {  // stage K tile [32][256]
      int row = t >> 3, i = t & 7;
      const ushort* src = kbase + (size_t)(kv * 32 + row) * 256;
#pragma unroll
      for (int j = 0; j < 4; ++j)
        *(uint4*)&Kls[row * 264 + (i + 8 * j) * 8] = *(const uint4*)(src + (i + 8 * j) * 8);
      // stage vT tile [256][32]
      const ushort* vs = vbase + (size_t)t * 4096 + kv * 32;
#pragma unroll
      for (int j = 0; j < 4; ++j)
        *(uint4*)&Vls[t * 40 + j * 8] = *(const uint4*)(vs + j * 8);
    }
    __syncthreads();

    // S^T = K . Q^T : D[kseq][q]
    f32x4 sacc0 = f32x4{0.f, 0.f, 0.f, 0.f};
    f32x4 sacc1 = f32x4{0.f, 0.f, 0.f, 0.f};
#pragma unroll
    for (int ct = 0; ct < 8; ++ct) {
      s16x8 k0 = *(const s16x8*)&Kls[lq * 264 + ct * 32 + lg * 8];
      s16x8 k1 = *(const s16x8*)&Kls[(16 + lq) * 264 + ct * 32 + lg * 8];
      sacc0 = MFMA16(k0, qf[ct], sacc0);
      sacc1 = MFMA16(k1, qf[ct], sacc1);
    }
    float sv[8];
#pragma unroll
    for (int r = 0; r < 4; ++r) {
      sv[r] = sacc0[r] * 0.0625f;
      sv[4 + r] = sacc1[r] * 0.0625f;
    }
    float mloc = sv[0];
#pragma unroll
    for (int i = 1; i < 8; ++i) mloc = fmaxf(mloc, sv[i]);
    mloc = fmaxf(mloc, __shfl_xor(mloc, 16));
    mloc = fmaxf(mloc, __shfl_xor(mloc, 32));
    float mnew = fmaxf(mrun, mloc);
    float alpha = __expf(mrun - mnew);
    float psum = 0.f;
    ushort pb[8];
#pragma unroll
    for (int i = 0; i < 8; ++i) {
      float p = __expf(sv[i] - mnew);
      psum += p;
      pb[i] = f2bf(p);
    }
    psum += __shfl_xor(psum, 16);
    psum += __shfl_xor(psum, 32);
    lrun = lrun * alpha + psum;
    mrun = mnew;

    *(uint2*)&Pls[w][lq * 40 + lg * 4] =
        make_uint2((uint)pb[0] | ((uint)pb[1] << 16), (uint)pb[2] | ((uint)pb[3] << 16));
    *(uint2*)&Pls[w][lq * 40 + 16 + lg * 4] =
        make_uint2((uint)pb[4] | ((uint)pb[5] << 16), (uint)pb[6] | ((uint)pb[7] << 16));
    if (lg == 0) as_[w][lq] = alpha;
    __asm__ volatile("s_waitcnt lgkmcnt(0)" ::: "memory");

    f32x4 av;
#pragma unroll
    for (int r = 0; r < 4; ++r) av[r] = as_[w][lg * 4 + r];
#pragma unroll
    for (int dt = 0; dt < 16; ++dt) oacc[dt] = oacc[dt] * av;

    s16x8 pf = *(const s16x8*)&Pls[w][lq * 40 + lg * 8];
#pragma unroll
    for (int dt = 0; dt < 16; ++dt) {
      s16x8 vf = *(const s16x8*)&Vls[(dt * 16 + lq) * 40 + lg * 8];
      oacc[dt] = MFMA16(pf, vf, oacc[dt]);
    }
  }

  if (lg == 0) ls_[w][lq] = lrun;
  __asm__ volatile("s_waitcnt lgkmcnt(0)" ::: "memory");
  float li[4];
#pragma unroll
  for (int r = 0; r < 4; ++r) li[r] = 1.f / ls_[w][lg * 4 + r];
  ushort* ob = o + ((size_t)(bb * 4096 + qt * 64 + w * 16 + lg * 4)) * 256 + lq;
#pragma unroll
  for (int dt = 0; dt < 16; ++dt)
#pragma unroll
    for (int r = 0; r < 4; ++r)
      ob[(size_t)r * 256 + dt * 16] = f2bf(oacc[dt][r] * li[r]);
}

extern "C" void kernel_launch(void* const* d_in, const int* in_sizes, int n_in,
                              void* d_out, int out_size, void* d_ws, size_t ws_size,
                              hipStream_t stream) {
  const float* x   = (const float*)d_in[0];
  const float* gnw = (const float*)d_in[1];
  const float* gnb = (const float*)d_in[2];
  const float* wq  = (const float*)d_in[3];
  const float* bq  = (const float*)d_in[4];
  const float* wk  = (const float*)d_in[5];
  const float* bk  = (const float*)d_in[6];
  const float* wv  = (const float*)d_in[7];
  const float* bv  = (const float*)d_in[8];
  const float* wp  = (const float*)d_in[9];
  const float* bp  = (const float*)d_in[10];

  const size_t SEQ = 4096, CH = 256;
  const size_t MAT = SEQ * CH;           // elements per [n][c] matrix per batch
  char* ws = (char*)d_ws;
  // each big buffer = 8 * 4096 * 256 * 2 bytes = 16 MiB
  const size_t BUF = 8 * MAT * 2;
  ushort* y    = (ushort*)(ws + 0 * BUF);
  ushort* qb   = (ushort*)(ws + 1 * BUF);
  ushort* kb_  = (ushort*)(ws + 2 * BUF);
  ushort* vtb  = (ushort*)(ws + 3 * BUF);
  ushort* oab  = y;  // y is dead after the V GEMM; reuse for attention output
  ushort* wqb  = (ushort*)(ws + 4 * BUF);
  ushort* wkb  = wqb + 65536;
  ushort* wvb  = wkb + 65536;
  ushort* wpb  = wvb + 65536;
  float* scaleB = (float*)(wpb + 65536);
  float* shiftB = scaleB + 8 * 256;

  cvt_w_kernel<<<64, 256, 0, stream>>>(wq, wk, wv, wp, wqb, wkb, wvb, wpb);
  gn_stats_kernel<<<64, 256, 0, stream>>>(x, gnw, gnb, scaleB, shiftB);
  gn_apply_kernel<<<2048, 256, 0, stream>>>(x, scaleB, shiftB, y);

  // q[n][o] = y . wq^T + bq(col)
  gemm_bt<0><<<dim3(64, 8), 256, 0, stream>>>(y, wqb, MAT, 0, 4096, 256, bq,
                                              nullptr, 0, qb, MAT);
  // k'[m][o] = y . wk^T + bk(col)
  gemm_bt<0><<<dim3(64, 8), 256, 0, stream>>>(y, wkb, MAT, 0, 4096, 256, bk,
                                              nullptr, 0, kb_, MAT);
  // vT[o][m] = wv . y^T + bv(row)
  gemm_bt<1><<<dim3(64, 8), 256, 0, stream>>>(wvb, y, 0, MAT, 256, 4096, bv,
                                              nullptr, 0, vtb, MAT);

  attn_kernel<<<512, 256, 0, stream>>>(qb, kb_, vtb, oab);

  // out[co][n] = wp . oattn^T + bp(row) + x   (f32)
  gemm_bt<2><<<dim3(64, 8), 256, 0, stream>>>(wpb, oab, 0, MAT, 256, 4096, bp,
                                              x, MAT, d_out, MAT);
}